// Round 3
// baseline (35.314 us; speedup 1.0000x reference)
//
#include <hip/hip_runtime.h>

// Problem constants
constexpr int kB   = 4;
constexpr int kC   = 64;
constexpr int kH   = 32;
constexpr int kW   = 32;
constexpr int kO   = 128;
constexpr int kG   = 4;
constexpr int kHW  = kH * kW;  // 1024

// Decomposition
constexpr int kNC  = 16;         // channel chunks
constexpr int kCPC = kC / kNC;   // 4 channels per chunk
constexpr int kWCH = kCPC * 9;   // 36 weight slots per chunk
constexpr int kOG  = 8;          // outputs per block
constexpr int kNOG = kO / kOG;   // 16 o-groups
constexpr int kTS  = 37;         // swizzled tile row stride (34 + rot 0..3)
constexpr int kTILE = 34 * kTS;  // 1258 floats per channel

// Grid = kNC * kB * kNOG = 1024 blocks, 256 threads.
// Block: stage 4 haloed channels once in LDS (rot-swizzled), build the
// 8x36 weight chunk in LDS, then each thread computes a 4x4 pixel tile
// for 2 outputs (x values reused across outputs).
__global__ __launch_bounds__(256, 4) void conv_part_kernel(
    const float* __restrict__ x,
    const float* __restrict__ means,
    const int*   __restrict__ col_idx,
    float*       __restrict__ part)
{
    __shared__ float tile[kCPC * kTILE];   // ~20.1 KB
    __shared__ float wloc[kOG * kWCH];     // 288 floats

    const int blk    = blockIdx.x;
    const int og     = blk & (kNOG - 1);
    const int b      = (blk >> 4) & (kB - 1);
    const int chunk  = blk >> 6;
    const int t      = threadIdx.x;
    const int o_base = og * kOG;
    const int s_base = chunk * kWCH;

    for (int i = t; i < kOG * kWCH; i += 256) wloc[i] = 0.f;
    __syncthreads();

    // ---- build weight chunk: 8 o's x 256 gather entries = 2048 ----
    {
        const int ol = t >> 5;        // 0..7 : local output
        const int j0 = t & 31;
        const int o  = o_base + ol;
        #pragma unroll
        for (int k = 0; k < 8; ++k) {
            const int j = j0 + k * 32;                 // 0..255
            const int s = col_idx[o * 256 + j];
            if (s >= s_base && s < s_base + kWCH)
                atomicAdd(&wloc[ol * kWCH + (s - s_base)],
                          means[o * kG + (j >> 6)]);
        }
    }

    // ---- stage 4 haloed 34x34 channels, rot-swizzled ----
    {
        const float* xb = x + ((size_t)b * kC + chunk * kCPC) * kHW;
        for (int i = t; i < kCPC * 34 * 34; i += 256) {
            const int ch  = i / 1156;
            const int rem = i - ch * 1156;
            const int rr  = rem / 34;
            const int cc  = rem - rr * 34;
            const int hr  = rr - 1, hc = cc - 1;
            float v = 0.f;
            if (hr >= 0 && hr < kH && hc >= 0 && hc < kW)
                v = xb[ch * kHW + hr * kW + hc];
            tile[ch * kTILE + rr * kTS + cc + ((rr >> 2) & 3)] = v;
        }
    }
    __syncthreads();

    // ---- compute: 2 outputs x 4x4 pixels per thread ----
    const int op0  = (t >> 6) * 2;          // local output pair base
    const int lane = t & 63;
    const int r0   = (lane >> 3) * 4;       // pixel row base
    const int c0   = (lane & 7) * 4;        // pixel col base

    float acc[2][4][4] = {};

    for (int ch = 0; ch < kCPC; ++ch) {
        float w0[9], w1[9];
        #pragma unroll
        for (int k = 0; k < 9; ++k) {
            w0[k] = wloc[(op0    ) * kWCH + ch * 9 + k];
            w1[k] = wloc[(op0 + 1) * kWCH + ch * 9 + k];
        }
        float xv[6][6];
        #pragma unroll
        for (int i = 0; i < 6; ++i) {
            const int row  = r0 + i;
            const int base = ch * kTILE + row * kTS + c0 + ((row >> 2) & 3);
            #pragma unroll
            for (int j = 0; j < 6; ++j)
                xv[i][j] = tile[base + j];
        }
        #pragma unroll
        for (int kh = 0; kh < 3; ++kh)
            #pragma unroll
            for (int kw = 0; kw < 3; ++kw) {
                const float a0 = w0[kh * 3 + kw];
                const float a1 = w1[kh * 3 + kw];
                #pragma unroll
                for (int i = 0; i < 4; ++i)
                    #pragma unroll
                    for (int j = 0; j < 4; ++j) {
                        acc[0][i][j] += a0 * xv[i + kh][j + kw];
                        acc[1][i][j] += a1 * xv[i + kh][j + kw];
                    }
            }
    }

    // ---- store partials (float4 rows) ----
    #pragma unroll
    for (int u = 0; u < 2; ++u) {
        const int o  = o_base + op0 + u;
        float* dst = part + (((size_t)chunk * kB + b) * kO + o) * kHW;
        #pragma unroll
        for (int i = 0; i < 4; ++i) {
            float4 v = make_float4(acc[u][i][0], acc[u][i][1],
                                   acc[u][i][2], acc[u][i][3]);
            *reinterpret_cast<float4*>(&dst[(r0 + i) * kW + c0]) = v;
        }
    }
}

// Sum kNC partials + bias -> out.
__global__ __launch_bounds__(256) void reduce_kernel(
    const float* __restrict__ part,
    const float* __restrict__ bias,
    float*       __restrict__ out)
{
    constexpr int kQ = kB * kO * kHW / 4;   // 131072 float4s
    const int i4 = blockIdx.x * 256 + threadIdx.x;
    if (i4 >= kQ) return;
    const float4* p4 = reinterpret_cast<const float4*>(part);
    float4 s = p4[i4];
    #pragma unroll
    for (int n = 1; n < kNC; ++n) {
        float4 v = p4[(size_t)n * kQ + i4];
        s.x += v.x; s.y += v.y; s.z += v.z; s.w += v.w;
    }
    const float bo = bias[((i4 * 4) >> 10) & (kO - 1)];
    s.x += bo; s.y += bo; s.z += bo; s.w += bo;
    reinterpret_cast<float4*>(out)[i4] = s;
}

// Fallback (ws too small): direct single-pass conv, block = (b,o).
__global__ __launch_bounds__(256) void conv_direct_kernel(
    const float* __restrict__ x,
    const float* __restrict__ means,
    const float* __restrict__ bias,
    const int*   __restrict__ col_idx,
    float*       __restrict__ out)
{
    __shared__ float tile[34 * 34];
    __shared__ float wloc[kC * 9];

    const int o = blockIdx.x & (kO - 1);
    const int b = blockIdx.x >> 7;
    const int t = threadIdx.x;

    for (int i = t; i < kC * 9; i += 256) wloc[i] = 0.f;
    __syncthreads();
    {
        const int s = col_idx[o * 256 + t];
        atomicAdd(&wloc[s], means[o * kG + (t >> 6)]);
    }

    const int c  = t & 31;
    const int r0 = (t >> 5) * 4;
    const float* xb = x + (size_t)b * kC * kHW;
    float acc[4] = {0.f, 0.f, 0.f, 0.f};

    for (int ch = 0; ch < kC; ++ch) {
        __syncthreads();
        for (int i = t; i < 34 * 34; i += 256) {
            const int rr = i / 34, cc = i - (i / 34) * 34;
            const int hr = rr - 1, hc = cc - 1;
            float v = 0.f;
            if (hr >= 0 && hr < kH && hc >= 0 && hc < kW)
                v = xb[ch * kHW + hr * kW + hc];
            tile[i] = v;
        }
        __syncthreads();
        float w[9];
        #pragma unroll
        for (int k = 0; k < 9; ++k) w[k] = wloc[ch * 9 + k];
        float xv[6][3];
        #pragma unroll
        for (int i = 0; i < 6; ++i)
            #pragma unroll
            for (int j = 0; j < 3; ++j)
                xv[i][j] = tile[(r0 + i) * 34 + c + j];
        #pragma unroll
        for (int i = 0; i < 4; ++i)
            #pragma unroll
            for (int kh = 0; kh < 3; ++kh)
                #pragma unroll
                for (int kw = 0; kw < 3; ++kw)
                    acc[i] += w[kh * 3 + kw] * xv[i + kh][kw];
    }
    const float bo = bias[o];
    #pragma unroll
    for (int i = 0; i < 4; ++i)
        out[(((size_t)b * kO + o)) * kHW + (r0 + i) * kW + c] = acc[i] + bo;
}

extern "C" void kernel_launch(void* const* d_in, const int* in_sizes, int n_in,
                              void* d_out, int out_size, void* d_ws, size_t ws_size,
                              hipStream_t stream)
{
    const float* x       = (const float*)d_in[0];
    const float* means   = (const float*)d_in[1];
    const float* bias    = (const float*)d_in[2];
    const int*   col_idx = (const int*)d_in[3];
    float*       out     = (float*)d_out;
    float*       part    = (float*)d_ws;

    constexpr size_t kPartBytes =
        (size_t)kNC * kB * kO * kHW * sizeof(float);   // 32 MB

    if (ws_size >= kPartBytes) {
        conv_part_kernel<<<kNC * kB * kNOG, 256, 0, stream>>>(
            x, means, col_idx, part);
        reduce_kernel<<<(kB * kO * kHW / 4) / 256, 256, 0, stream>>>(
            part, bias, out);
    } else {
        conv_direct_kernel<<<kB * kO, 256, 0, stream>>>(
            x, means, bias, col_idx, out);
    }
}

// Round 5
// 29.177 us; speedup vs baseline: 1.2103x; 1.2103x over previous
//
#include <hip/hip_runtime.h>

// Problem constants
constexpr int kB   = 4;
constexpr int kC   = 64;
constexpr int kH   = 32;
constexpr int kW   = 32;
constexpr int kO   = 128;
constexpr int kG   = 4;
constexpr int kHW  = kH * kW;  // 1024

// Decomposition
constexpr int kNC   = 8;           // channel chunks
constexpr int kCPC  = kC / kNC;    // 8 channels per chunk
constexpr int kOG   = 8;           // outputs per block
constexpr int kNOG  = kO / kOG;    // 16 o-groups
constexpr int kWP   = 12;          // padded weight row (9 -> 12 for b128)
constexpr int kTS   = 48;          // tile row stride: 34 + max rot 12, 16B-aligned
constexpr int kTILE = 34 * kTS;    // 1632 floats per channel

__device__ __forceinline__ int rot4(int r) { return r & 12; } // 0,4,8,12 per 4-row group

// Grid = kNC*kB*kNOG = 512 blocks, 256 threads.
// XCD swizzle: each XCD (blockIdx%8) owns one channel chunk (64 logical ids).
__global__ __launch_bounds__(256, 2) void conv_part_kernel(
    const float* __restrict__ x,
    const float* __restrict__ means,
    const int*   __restrict__ col_idx,
    float*       __restrict__ part)
{
    __shared__ float tile[kCPC * kTILE];        // 52.2 KB
    __shared__ float wloc[kOG * kCPC * kWP];    // 3 KB

    // logical id: XCD-contiguous chunks
    const int logical = (blockIdx.x & 7) * 64 + (blockIdx.x >> 3);
    const int og     = logical & (kNOG - 1);
    const int b      = (logical >> 4) & (kB - 1);
    const int chunk  = logical >> 6;
    const int t      = threadIdx.x;
    const int o_base = og * kOG;
    const int s_base = chunk * (kCPC * 9);

    for (int i = t; i < kOG * kCPC * kWP; i += 256) wloc[i] = 0.f;
    __syncthreads();

    // ---- build weight chunk: 8 o's x 256 gather entries ----
    {
        const int ol = t >> 5;
        const int j0 = t & 31;
        const int o  = o_base + ol;
        #pragma unroll
        for (int k = 0; k < 8; ++k) {
            const int j = j0 + k * 32;
            const int s = col_idx[o * 256 + j] - s_base;
            if (s >= 0 && s < kCPC * 9) {
                const int ch_l = s / 9;
                const int kk   = s - ch_l * 9;
                atomicAdd(&wloc[(ol * kCPC + ch_l) * kWP + kk],
                          means[o * kG + (j >> 6)]);
            }
        }
    }

    // ---- stage 8 haloed channels, rot-swizzled, vectorized ----
    {
        const float* xb = x + ((size_t)b * kC + chunk * kCPC) * kHW;
        #pragma unroll
        for (int pass = 0; pass < 2; ++pass) {
            const int tau = t + pass * 256;
            if (pass == 0 || t < kCPC * 34 - 256) {
                const int ch = tau / 34;
                const int rr = tau - ch * 34;
                const int hr = rr - 1;
                float4 v[8];
                if (hr >= 0 && hr < kH) {
                    const float4* s4 =
                        reinterpret_cast<const float4*>(xb + ch * kHW + hr * kW);
                    #pragma unroll
                    for (int q = 0; q < 8; ++q) v[q] = s4[q];
                } else {
                    #pragma unroll
                    for (int q = 0; q < 8; ++q)
                        v[q] = make_float4(0.f, 0.f, 0.f, 0.f);
                }
                float* tp = &tile[ch * kTILE + rr * kTS + rot4(rr)];
                float prev = 0.f;
                #pragma unroll
                for (int q = 0; q < 8; ++q) {
                    *reinterpret_cast<float4*>(&tp[4 * q]) =
                        make_float4(prev, v[q].x, v[q].y, v[q].z);
                    prev = v[q].w;
                }
                *reinterpret_cast<float2*>(&tp[32]) = make_float2(prev, 0.f);
            }
        }
    }
    __syncthreads();

    // ---- compute: 2 outputs x 4x4 pixels per thread ----
    const int op0  = (t >> 6) * 2;
    const int lane = t & 63;
    const int r0   = (lane >> 3) * 4;
    const int c0   = (lane & 7) * 4;

    float acc[2][4][4] = {};

    for (int ch = 0; ch < kCPC; ++ch) {
        // x patch: 6 rows, b128 + b64 each
        float xv[6][6];
        #pragma unroll
        for (int i = 0; i < 6; ++i) {
            const int row = r0 + i;
            const float* rp = &tile[ch * kTILE + row * kTS + rot4(row) + c0];
            const float4 a  = *reinterpret_cast<const float4*>(rp);
            const float2 bb = *reinterpret_cast<const float2*>(rp + 4);
            xv[i][0] = a.x;  xv[i][1] = a.y;  xv[i][2] = a.z;
            xv[i][3] = a.w;  xv[i][4] = bb.x; xv[i][5] = bb.y;
        }
        // weights: wave-uniform LDS broadcast, vectorized
        float w0[9], w1[9];
        {
            const float* wp = &wloc[(op0 * kCPC + ch) * kWP];
            const float4 wa = *reinterpret_cast<const float4*>(wp);
            const float4 wb = *reinterpret_cast<const float4*>(wp + 4);
            w0[0]=wa.x; w0[1]=wa.y; w0[2]=wa.z; w0[3]=wa.w;
            w0[4]=wb.x; w0[5]=wb.y; w0[6]=wb.z; w0[7]=wb.w; w0[8]=wp[8];
            const float* wq = &wloc[((op0 + 1) * kCPC + ch) * kWP];
            const float4 wc = *reinterpret_cast<const float4*>(wq);
            const float4 wd = *reinterpret_cast<const float4*>(wq + 4);
            w1[0]=wc.x; w1[1]=wc.y; w1[2]=wc.z; w1[3]=wc.w;
            w1[4]=wd.x; w1[5]=wd.y; w1[6]=wd.z; w1[7]=wd.w; w1[8]=wq[8];
        }
        #pragma unroll
        for (int kh = 0; kh < 3; ++kh)
            #pragma unroll
            for (int kw = 0; kw < 3; ++kw) {
                const float a0 = w0[kh * 3 + kw];
                const float a1 = w1[kh * 3 + kw];
                #pragma unroll
                for (int i = 0; i < 4; ++i)
                    #pragma unroll
                    for (int j = 0; j < 4; ++j) {
                        acc[0][i][j] += a0 * xv[i + kh][j + kw];
                        acc[1][i][j] += a1 * xv[i + kh][j + kw];
                    }
            }
    }

    #pragma unroll
    for (int u = 0; u < 2; ++u) {
        const int o = o_base + op0 + u;
        float* dst  = part + (((size_t)chunk * kB + b) * kO + o) * kHW;
        #pragma unroll
        for (int i = 0; i < 4; ++i)
            *reinterpret_cast<float4*>(&dst[(r0 + i) * kW + c0]) =
                make_float4(acc[u][i][0], acc[u][i][1],
                            acc[u][i][2], acc[u][i][3]);
    }
}

// Sum kNC partials + bias -> out. Grid = 512 x 256 covers all float4s.
__global__ __launch_bounds__(256) void reduce_kernel(
    const float* __restrict__ part,
    const float* __restrict__ bias,
    float*       __restrict__ out)
{
    constexpr int kQ = kB * kO * kHW / 4;   // 131072 float4s
    const int i4 = blockIdx.x * 256 + threadIdx.x;
    const float4* p4 = reinterpret_cast<const float4*>(part);
    float4 s = p4[i4];
    #pragma unroll
    for (int n = 1; n < kNC; ++n) {
        const float4 v = p4[(size_t)n * kQ + i4];
        s.x += v.x; s.y += v.y; s.z += v.z; s.w += v.w;
    }
    const float bo = bias[(i4 >> 8) & (kO - 1)];
    s.x += bo; s.y += bo; s.z += bo; s.w += bo;
    reinterpret_cast<float4*>(out)[i4] = s;
}

// Fallback (ws too small): direct single-pass conv, block = (b,o).
__global__ __launch_bounds__(256) void conv_direct_kernel(
    const float* __restrict__ x,
    const float* __restrict__ means,
    const float* __restrict__ bias,
    const int*   __restrict__ col_idx,
    float*       __restrict__ out)
{
    __shared__ float tile[34 * 34];
    __shared__ float wloc[kC * 9];

    const int o = blockIdx.x & (kO - 1);
    const int b = blockIdx.x >> 7;
    const int t = threadIdx.x;

    for (int i = t; i < kC * 9; i += 256) wloc[i] = 0.f;
    __syncthreads();
    {
        const int s = col_idx[o * 256 + t];
        atomicAdd(&wloc[s], means[o * kG + (t >> 6)]);
    }

    const int c  = t & 31;
    const int r0 = (t >> 5) * 4;
    const float* xb = x + (size_t)b * kC * kHW;
    float acc[4] = {0.f, 0.f, 0.f, 0.f};

    for (int ch = 0; ch < kC; ++ch) {
        __syncthreads();
        for (int i = t; i < 34 * 34; i += 256) {
            const int rr = i / 34, cc = i - rr * 34;
            const int hr = rr - 1, hc = cc - 1;
            float v = 0.f;
            if (hr >= 0 && hr < kH && hc >= 0 && hc < kW)
                v = xb[ch * kHW + hr * kW + hc];
            tile[i] = v;
        }
        __syncthreads();
        float w[9];
        #pragma unroll
        for (int k = 0; k < 9; ++k) w[k] = wloc[ch * 9 + k];
        float xv[6][3];
        #pragma unroll
        for (int i = 0; i < 6; ++i)
            #pragma unroll
            for (int j = 0; j < 3; ++j)
                xv[i][j] = tile[(r0 + i) * 34 + c + j];
        #pragma unroll
        for (int i = 0; i < 4; ++i)
            #pragma unroll
            for (int kh = 0; kh < 3; ++kh)
                #pragma unroll
                for (int kw = 0; kw < 3; ++kw)
                    acc[i] += w[kh * 3 + kw] * xv[i + kh][kw];
    }
    const float bo = bias[o];
    #pragma unroll
    for (int i = 0; i < 4; ++i)
        out[((size_t)b * kO + o) * kHW + (r0 + i) * kW + c] = acc[i] + bo;
}

extern "C" void kernel_launch(void* const* d_in, const int* in_sizes, int n_in,
                              void* d_out, int out_size, void* d_ws, size_t ws_size,
                              hipStream_t stream)
{
    const float* x       = (const float*)d_in[0];
    const float* means   = (const float*)d_in[1];
    const float* bias    = (const float*)d_in[2];
    const int*   col_idx = (const int*)d_in[3];
    float*       out     = (float*)d_out;
    float*       part    = (float*)d_ws;

    constexpr size_t kPartBytes =
        (size_t)kNC * kB * kO * kHW * sizeof(float);   // 16 MB

    if (ws_size >= kPartBytes) {
        conv_part_kernel<<<kNC * kB * kNOG, 256, 0, stream>>>(
            x, means, col_idx, part);
        reduce_kernel<<<(kB * kO * kHW / 4) / 256, 256, 0, stream>>>(
            part, bias, out);
    } else {
        conv_direct_kernel<<<kB * kO, 256, 0, stream>>>(
            x, means, bias, col_idx, out);
    }
}

// Round 6
// 21.752 us; speedup vs baseline: 1.6235x; 1.3414x over previous
//
#include <hip/hip_runtime.h>
#include <hip/hip_bf16.h>

// Problem constants
constexpr int kB   = 4;
constexpr int kC   = 64;
constexpr int kH   = 32;
constexpr int kW   = 32;
constexpr int kO   = 128;
constexpr int kG   = 4;
constexpr int kHW  = kH * kW;  // 1024

// Decomposition
constexpr int kNC   = 8;           // channel chunks
constexpr int kCPC  = kC / kNC;    // 8 channels per chunk
constexpr int kOG   = 8;           // outputs per block
constexpr int kNOG  = kO / kOG;    // 16 o-groups
constexpr int kWP   = 12;          // padded weight row (9 -> 12)
constexpr int kTS   = 48;          // tile row stride: 34 + max rot 12, 16B-aligned
constexpr int kTILE = 34 * kTS;    // floats per channel

__device__ __forceinline__ int rot4(int r) { return r & 12; }

// Grid = 512 blocks, 256 threads.
// Block decode keeps XCD (blockIdx%8) == og&7 so a block's partial writes
// stay in the XCD's L2 that the matching reduce block will read from.
__global__ __launch_bounds__(256, 2) void conv_part_kernel(
    const float* __restrict__ x,
    const float* __restrict__ means,
    const int*   __restrict__ col_idx,
    __hip_bfloat16* __restrict__ part)
{
    __shared__ float tile[kCPC * kTILE];        // 52.2 KB
    __shared__ float wloc[kOG * kCPC * kWP];    // 3 KB

    const int idx   = blockIdx.x;
    const int og    = (idx & 7) | (((idx >> 3) & 1) << 3);
    const int b     = (idx >> 4) & 3;
    const int chunk = idx >> 6;
    const int t     = threadIdx.x;
    const int o_base = og * kOG;
    const int s_base = chunk * (kCPC * 9);

    // ---- A) issue col_idx + means loads early ----
    const int ol  = t >> 5;
    const int j0  = t & 31;
    const int o_w = o_base + ol;
    int sidx[8];
    #pragma unroll
    for (int k = 0; k < 8; ++k)
        sidx[k] = col_idx[o_w * 256 + j0 + k * 32];
    const float4 mrow = *reinterpret_cast<const float4*>(&means[o_w * kG]);

    // ---- B) issue x loads early (regs), write LDS later ----
    const float* xb = x + ((size_t)b * kC + chunk * kCPC) * kHW;
    float4 v[2][8];
    int ch_[2], rr_[2];
    #pragma unroll
    for (int p = 0; p < 2; ++p) {
        const int tau = t + p * 256;
        ch_[p] = tau / 34;
        rr_[p] = tau - ch_[p] * 34;
        if (p == 0 || t < kCPC * 34 - 256) {
            const int hr = rr_[p] - 1;
            if (hr >= 0 && hr < kH) {
                const float4* s4 =
                    reinterpret_cast<const float4*>(xb + ch_[p] * kHW + hr * kW);
                #pragma unroll
                for (int q = 0; q < 8; ++q) v[p][q] = s4[q];
            } else {
                #pragma unroll
                for (int q = 0; q < 8; ++q)
                    v[p][q] = make_float4(0.f, 0.f, 0.f, 0.f);
            }
        }
    }

    // ---- C) build weight chunk under the load latency ----
    for (int i = t; i < kOG * kCPC * kWP; i += 256) wloc[i] = 0.f;
    __syncthreads();
    {
        const float* mr = reinterpret_cast<const float*>(&mrow);
        #pragma unroll
        for (int k = 0; k < 8; ++k) {
            const int s = sidx[k] - s_base;
            if (s >= 0 && s < kCPC * 9) {
                const int ch_l = s / 9;
                const int kk   = s - ch_l * 9;
                atomicAdd(&wloc[(ol * kCPC + ch_l) * kWP + kk], mr[k >> 1]);
            }
        }
    }

    // ---- D) write staged x into rot-swizzled LDS tile ----
    #pragma unroll
    for (int p = 0; p < 2; ++p) {
        if (p == 0 || t < kCPC * 34 - 256) {
            float* tp = &tile[ch_[p] * kTILE + rr_[p] * kTS + rot4(rr_[p])];
            float prev = 0.f;
            #pragma unroll
            for (int q = 0; q < 8; ++q) {
                *reinterpret_cast<float4*>(&tp[4 * q]) =
                    make_float4(prev, v[p][q].x, v[p][q].y, v[p][q].z);
                prev = v[p][q].w;
            }
            *reinterpret_cast<float2*>(&tp[32]) = make_float2(prev, 0.f);
        }
    }
    __syncthreads();

    // ---- E) compute: 2 outputs x 4x4 pixels per thread ----
    const int op0  = (t >> 6) * 2;
    const int lane = t & 63;
    const int r0   = (lane >> 3) * 4;
    const int c0   = (lane & 7) * 4;

    float acc[2][4][4] = {};

    for (int ch = 0; ch < kCPC; ++ch) {
        float xv[6][6];
        #pragma unroll
        for (int i = 0; i < 6; ++i) {
            const int row = r0 + i;
            const float* rp = &tile[ch * kTILE + row * kTS + rot4(row) + c0];
            const float4 a  = *reinterpret_cast<const float4*>(rp);
            const float2 bb = *reinterpret_cast<const float2*>(rp + 4);
            xv[i][0] = a.x;  xv[i][1] = a.y;  xv[i][2] = a.z;
            xv[i][3] = a.w;  xv[i][4] = bb.x; xv[i][5] = bb.y;
        }
        float w0[9], w1[9];
        {
            const float* wp = &wloc[(op0 * kCPC + ch) * kWP];
            const float4 wa = *reinterpret_cast<const float4*>(wp);
            const float4 wb = *reinterpret_cast<const float4*>(wp + 4);
            w0[0]=wa.x; w0[1]=wa.y; w0[2]=wa.z; w0[3]=wa.w;
            w0[4]=wb.x; w0[5]=wb.y; w0[6]=wb.z; w0[7]=wb.w; w0[8]=wp[8];
            const float* wq = &wloc[((op0 + 1) * kCPC + ch) * kWP];
            const float4 wc = *reinterpret_cast<const float4*>(wq);
            const float4 wd = *reinterpret_cast<const float4*>(wq + 4);
            w1[0]=wc.x; w1[1]=wc.y; w1[2]=wc.z; w1[3]=wc.w;
            w1[4]=wd.x; w1[5]=wd.y; w1[6]=wd.z; w1[7]=wd.w; w1[8]=wq[8];
        }
        #pragma unroll
        for (int kh = 0; kh < 3; ++kh)
            #pragma unroll
            for (int kw = 0; kw < 3; ++kw) {
                const float a0 = w0[kh * 3 + kw];
                const float a1 = w1[kh * 3 + kw];
                #pragma unroll
                for (int i = 0; i < 4; ++i)
                    #pragma unroll
                    for (int j = 0; j < 4; ++j) {
                        acc[0][i][j] += a0 * xv[i + kh][j + kw];
                        acc[1][i][j] += a1 * xv[i + kh][j + kw];
                    }
            }
    }

    // ---- F) store bf16 partials (8B per row of 4) ----
    #pragma unroll
    for (int u = 0; u < 2; ++u) {
        const int o = o_base + op0 + u;
        __hip_bfloat16* dst =
            part + (((size_t)chunk * kB + b) * kO + o) * kHW;
        #pragma unroll
        for (int i = 0; i < 4; ++i) {
            __hip_bfloat162 lo, hi;
            lo.x = __float2bfloat16(acc[u][i][0]);
            lo.y = __float2bfloat16(acc[u][i][1]);
            hi.x = __float2bfloat16(acc[u][i][2]);
            hi.y = __float2bfloat16(acc[u][i][3]);
            union { __hip_bfloat162 h2[2]; uint2 u2; } pk;
            pk.h2[0] = lo; pk.h2[1] = hi;
            *reinterpret_cast<uint2*>(&dst[(r0 + i) * kW + c0]) = pk.u2;
        }
    }
}

// Sum kNC bf16 partials + bias -> fp32 out. 512 blocks x 256 threads.
// Block <-> one (b,o); placed on the XCD class (o>>3)&7 that wrote it.
__global__ __launch_bounds__(256) void reduce_kernel(
    const __hip_bfloat16* __restrict__ part,
    const float* __restrict__ bias,
    float* __restrict__ out)
{
    const int idx = blockIdx.x;
    const int t   = threadIdx.x;
    const int g    = idx & 7;
    const int r    = idx >> 3;
    const int oghi = r & 1;
    const int o_lo = (r >> 1) & 7;
    const int b    = r >> 4;
    const int o    = (((oghi << 3) | g) << 3) | o_lo;

    float s0 = 0.f, s1 = 0.f, s2 = 0.f, s3 = 0.f;
    #pragma unroll
    for (int n = 0; n < kNC; ++n) {
        const __hip_bfloat16* p =
            part + (((size_t)n * kB + b) * kO + o) * kHW + t * 4;
        union { uint2 u2; __hip_bfloat162 h2[2]; } pk;
        pk.u2 = *reinterpret_cast<const uint2*>(p);
        s0 += __bfloat162float(pk.h2[0].x);
        s1 += __bfloat162float(pk.h2[0].y);
        s2 += __bfloat162float(pk.h2[1].x);
        s3 += __bfloat162float(pk.h2[1].y);
    }
    const float bo = bias[o];
    float4 res = make_float4(s0 + bo, s1 + bo, s2 + bo, s3 + bo);
    reinterpret_cast<float4*>(out)[((size_t)(b * kO + o)) * (kHW / 4) + t] = res;
}

// Fallback (ws too small): direct single-pass conv, block = (b,o).
__global__ __launch_bounds__(256) void conv_direct_kernel(
    const float* __restrict__ x,
    const float* __restrict__ means,
    const float* __restrict__ bias,
    const int*   __restrict__ col_idx,
    float*       __restrict__ out)
{
    __shared__ float tile[34 * 34];
    __shared__ float wloc[kC * 9];

    const int o = blockIdx.x & (kO - 1);
    const int b = blockIdx.x >> 7;
    const int t = threadIdx.x;

    for (int i = t; i < kC * 9; i += 256) wloc[i] = 0.f;
    __syncthreads();
    {
        const int s = col_idx[o * 256 + t];
        atomicAdd(&wloc[s], means[o * kG + (t >> 6)]);
    }

    const int c  = t & 31;
    const int r0 = (t >> 5) * 4;
    const float* xb = x + (size_t)b * kC * kHW;
    float acc[4] = {0.f, 0.f, 0.f, 0.f};

    for (int ch = 0; ch < kC; ++ch) {
        __syncthreads();
        for (int i = t; i < 34 * 34; i += 256) {
            const int rr = i / 34, cc = i - rr * 34;
            const int hr = rr - 1, hc = cc - 1;
            float v = 0.f;
            if (hr >= 0 && hr < kH && hc >= 0 && hc < kW)
                v = xb[ch * kHW + hr * kW + hc];
            tile[i] = v;
        }
        __syncthreads();
        float w[9];
        #pragma unroll
        for (int k = 0; k < 9; ++k) w[k] = wloc[ch * 9 + k];
        float xv[6][3];
        #pragma unroll
        for (int i = 0; i < 6; ++i)
            #pragma unroll
            for (int j = 0; j < 3; ++j)
                xv[i][j] = tile[(r0 + i) * 34 + c + j];
        #pragma unroll
        for (int i = 0; i < 4; ++i)
            #pragma unroll
            for (int kh = 0; kh < 3; ++kh)
                #pragma unroll
                for (int kw = 0; kw < 3; ++kw)
                    acc[i] += w[kh * 3 + kw] * xv[i + kh][kw];
    }
    const float bo = bias[o];
    #pragma unroll
    for (int i = 0; i < 4; ++i)
        out[((size_t)b * kO + o) * kHW + (r0 + i) * kW + c] = acc[i] + bo;
}

extern "C" void kernel_launch(void* const* d_in, const int* in_sizes, int n_in,
                              void* d_out, int out_size, void* d_ws, size_t ws_size,
                              hipStream_t stream)
{
    const float* x       = (const float*)d_in[0];
    const float* means   = (const float*)d_in[1];
    const float* bias    = (const float*)d_in[2];
    const int*   col_idx = (const int*)d_in[3];
    float*       out     = (float*)d_out;

    constexpr size_t kPartBytes =
        (size_t)kNC * kB * kO * kHW * sizeof(__hip_bfloat16);   // 8 MB

    if (ws_size >= kPartBytes) {
        __hip_bfloat16* part = (__hip_bfloat16*)d_ws;
        conv_part_kernel<<<kNC * kB * kNOG, 256, 0, stream>>>(
            x, means, col_idx, part);
        reduce_kernel<<<kB * kO, 256, 0, stream>>>(part, bias, out);
    } else {
        conv_direct_kernel<<<kB * kO, 256, 0, stream>>>(
            x, means, bias, col_idx, out);
    }
}